// Round 2
// baseline (2254.194 us; speedup 1.0000x reference)
//
#include <hip/hip_runtime.h>
#include <math.h>

#define BATCH    65536
#define HID      128
#define SELF_DIM 18
#define NBR_DIM  6
#define IN_DIM   24      // SELF_DIM + NBR_DIM
#define OBS_W    66      // SELF_DIM + 8*NBR_DIM
#define RB       32      // rows per block (4 groups of 8)
#define NGRP     4
#define NTHREADS 256

__device__ __forceinline__ float tanh_f(float x) {
    x = fminf(15.f, fmaxf(-15.f, x));
    float t = __expf(2.f * x);
    return (t - 1.f) / (t + 1.f);
}

__device__ __forceinline__ float4 ld4(const float* p) { return *reinterpret_cast<const float4*>(p); }
__device__ __forceinline__ void st4(float* p, float4 v) { *reinterpret_cast<float4*>(p) = v; }

// stage KC x 128 weight rows into Wbuf (coalesced float4)
template<int KC>
__device__ __forceinline__ void stage_w(float (*Wbuf)[HID], const float* __restrict__ W, int tid) {
    const float4* __restrict__ Wg = reinterpret_cast<const float4*>(W);
    float4* Wl = reinterpret_cast<float4*>(&Wbuf[0][0]);
    constexpr int NV = KC * HID / 4;
    for (int u = tid; u < NV; u += NTHREADS) Wl[u] = Wg[u];
}

// acc[q][c] += sum_i IN[(s0+q)*STR + ibase + i] * Wbuf[i][j4+c]
template<int KC, int STR>
__device__ __forceinline__ void accum_rows(float acc[4][4], const float (*Wbuf)[HID],
                                           const float* __restrict__ IN,
                                           int s0, int ibase, int j4) {
    #pragma unroll 4
    for (int i = 0; i < KC; i += 4) {
        float4 w0 = ld4(&Wbuf[i + 0][j4]);
        float4 w1 = ld4(&Wbuf[i + 1][j4]);
        float4 w2 = ld4(&Wbuf[i + 2][j4]);
        float4 w3 = ld4(&Wbuf[i + 3][j4]);
        #pragma unroll
        for (int q = 0; q < 4; ++q) {
            float4 x = ld4(IN + (s0 + q) * STR + ibase + i);
            acc[q][0] += x.x * w0.x + x.y * w1.x + x.z * w2.x + x.w * w3.x;
            acc[q][1] += x.x * w0.y + x.y * w1.y + x.z * w2.y + x.w * w3.y;
            acc[q][2] += x.x * w0.z + x.y * w1.z + x.z * w2.z + x.w * w3.z;
            acc[q][3] += x.x * w0.w + x.y * w1.w + x.z * w2.w + x.w * w3.w;
        }
    }
}

__device__ __forceinline__ void zero_acc(float acc[4][4]) {
    #pragma unroll
    for (int q = 0; q < 4; ++q)
        #pragma unroll
        for (int c = 0; c < 4; ++c) acc[q][c] = 0.f;
}

// build X0 rows: row r -> [self_obs[r % B], obs[r/8][18 + 6*(r%8) ..]]
__device__ __forceinline__ void build_x0(float* __restrict__ X0, // [RB][IN_DIM] flat
                                         const float* __restrict__ self_obs,
                                         const float* __restrict__ obs,
                                         int r0, int tid) {
    for (int idx = tid; idx < RB * IN_DIM; idx += NTHREADS) {
        int s = idx / IN_DIM, c = idx - s * IN_DIM;
        int r = r0 + s;
        float v;
        if (c < SELF_DIM) v = self_obs[(r & (BATCH - 1)) * SELF_DIM + c];
        else              v = obs[(r >> 3) * OBS_W + SELF_DIM + (r & 7) * NBR_DIM + (c - SELF_DIM)];
        X0[s * IN_DIM + c] = v;
    }
}

// =============== Kernel A: emb -> group means (to ws) =======================
__global__ __launch_bounds__(NTHREADS, 2)
void emb_mean_k(const float* __restrict__ self_obs, const float* __restrict__ obs,
                const float* __restrict__ eW1, const float* __restrict__ eb1,
                const float* __restrict__ eW2, const float* __restrict__ eb2,
                float* __restrict__ meanbuf)
{
    __shared__ float Wbuf[64][HID];
    __shared__ float Abuf[RB][HID];
    __shared__ float Ebuf[RB][HID];
    __shared__ float X0s[RB][IN_DIM];

    const int tid = threadIdx.x;
    const int jg = tid & 31, sg = tid >> 5;
    const int j4 = jg * 4, s0 = sg * 4;
    const int r0 = blockIdx.x * RB;

    build_x0(&X0s[0][0], self_obs, obs, r0, tid);

    float acc[4][4];

    // L1
    __syncthreads();
    stage_w<IN_DIM>(Wbuf, eW1, tid);
    zero_acc(acc);
    __syncthreads();
    accum_rows<IN_DIM, IN_DIM>(acc, Wbuf, &X0s[0][0], s0, 0, j4);
    {
        float4 bb = ld4(&eb1[j4]);
        #pragma unroll
        for (int q = 0; q < 4; ++q) {
            float4 o;
            o.x = tanh_f(acc[q][0] + bb.x); o.y = tanh_f(acc[q][1] + bb.y);
            o.z = tanh_f(acc[q][2] + bb.z); o.w = tanh_f(acc[q][3] + bb.w);
            st4(&Abuf[s0 + q][j4], o);
        }
    }

    // L2
    zero_acc(acc);
    #pragma unroll
    for (int ch = 0; ch < 2; ++ch) {
        __syncthreads();
        stage_w<64>(Wbuf, eW2 + ch * 64 * HID, tid);
        __syncthreads();
        accum_rows<64, HID>(acc, Wbuf, &Abuf[0][0], s0, ch * 64, j4);
    }
    {
        float4 bb = ld4(&eb2[j4]);
        #pragma unroll
        for (int q = 0; q < 4; ++q) {
            float4 o;
            o.x = tanh_f(acc[q][0] + bb.x); o.y = tanh_f(acc[q][1] + bb.y);
            o.z = tanh_f(acc[q][2] + bb.z); o.w = tanh_f(acc[q][3] + bb.w);
            st4(&Ebuf[s0 + q][j4], o);
        }
    }

    // group means -> ws
    __syncthreads();
    for (int idx = tid; idx < NGRP * HID; idx += NTHREADS) {
        int g = idx >> 7, j = idx & 127;
        float s = 0.f;
        #pragma unroll
        for (int k = 0; k < 8; ++k) s += Ebuf[g * 8 + k][j];
        meanbuf[(blockIdx.x * NGRP + g) * HID + j] = s * 0.125f;
    }
}

// =============== Kernel B: full pipeline (means from ws) ====================
__global__ __launch_bounds__(NTHREADS, 2)
void quad_attn_main(const float* __restrict__ self_obs, const float* __restrict__ obs,
                    const float* __restrict__ eW1, const float* __restrict__ eb1,
                    const float* __restrict__ eW2, const float* __restrict__ eb2,
                    const float* __restrict__ vW1, const float* __restrict__ vb1,
                    const float* __restrict__ vW2, const float* __restrict__ vb2,
                    const float* __restrict__ aW1, const float* __restrict__ ab1,
                    const float* __restrict__ aW2, const float* __restrict__ ab2,
                    const float* __restrict__ aW3, const float* __restrict__ ab3,
                    const float* __restrict__ meanbuf,
                    float* __restrict__ out)
{
    __shared__ float Wbuf[64][HID];   // 32 KB weight chunk
    __shared__ float Abuf[RB][HID];   // 16 KB scratch activations
    __shared__ float Ebuf[RB][HID];   // 16 KB embedding (persists)
    __shared__ float Ubuf[RB][HID];   // 16 KB time-shared: X0 -> mean rows -> score/attn

    const int tid = threadIdx.x;
    const int jg = tid & 31, sg = tid >> 5;
    const int j4 = jg * 4, s0 = sg * 4;
    const int r0 = blockIdx.x * RB;

    float* Uflat = &Ubuf[0][0];
    float* scoreb = Uflat;        // [RB]   (valid after Mrow is dead)
    float* attnb  = Uflat + RB;   // [RB]

    build_x0(Uflat, self_obs, obs, r0, tid);   // Ubuf as X0 [RB][24]

    float acc[4][4];

    // ---- L1: X0 @ eW1 -> tanh -> Abuf
    __syncthreads();
    stage_w<IN_DIM>(Wbuf, eW1, tid);
    zero_acc(acc);
    __syncthreads();
    accum_rows<IN_DIM, IN_DIM>(acc, Wbuf, Uflat, s0, 0, j4);
    {
        float4 bb = ld4(&eb1[j4]);
        #pragma unroll
        for (int q = 0; q < 4; ++q) {
            float4 o;
            o.x = tanh_f(acc[q][0] + bb.x); o.y = tanh_f(acc[q][1] + bb.y);
            o.z = tanh_f(acc[q][2] + bb.z); o.w = tanh_f(acc[q][3] + bb.w);
            st4(&Abuf[s0 + q][j4], o);
        }
    }

    // ---- L2: Abuf @ eW2 -> tanh -> Ebuf; also load mean rows into Ubuf
    zero_acc(acc);
    #pragma unroll
    for (int ch = 0; ch < 2; ++ch) {
        __syncthreads();   // ch0: also guarantees all L1 reads of Ubuf-as-X0 are done
        stage_w<64>(Wbuf, eW2 + ch * 64 * HID, tid);
        if (ch == 0) {
            // mean rows needed: (r0 % B) + s for s in [0,32) — contiguous, no wrap
            const float4* mg = reinterpret_cast<const float4*>(meanbuf + (size_t)(r0 & (BATCH - 1)) * HID);
            float4* ul = reinterpret_cast<float4*>(Uflat);
            for (int u = tid; u < RB * HID / 4; u += NTHREADS) ul[u] = mg[u];
        }
        __syncthreads();
        accum_rows<64, HID>(acc, Wbuf, &Abuf[0][0], s0, ch * 64, j4);
    }
    {
        float4 bb = ld4(&eb2[j4]);
        #pragma unroll
        for (int q = 0; q < 4; ++q) {
            float4 o;
            o.x = tanh_f(acc[q][0] + bb.x); o.y = tanh_f(acc[q][1] + bb.y);
            o.z = tanh_f(acc[q][2] + bb.z); o.w = tanh_f(acc[q][3] + bb.w);
            st4(&Ebuf[s0 + q][j4], o);
        }
    }

    // ---- L5: tanh([emb, mean_rep] @ aW1 + ab1) -> Abuf
    //      aW1 rows 0..127 multiply emb (Ebuf), rows 128..255 multiply mean (Ubuf)
    zero_acc(acc);
    #pragma unroll
    for (int ch = 0; ch < 4; ++ch) {
        __syncthreads();
        stage_w<64>(Wbuf, aW1 + ch * 64 * HID, tid);
        __syncthreads();
        if (ch < 2) accum_rows<64, HID>(acc, Wbuf, &Ebuf[0][0], s0, ch * 64, j4);
        else        accum_rows<64, HID>(acc, Wbuf, Uflat,      s0, (ch - 2) * 64, j4);
    }
    {
        float4 bb = ld4(&ab1[j4]);
        #pragma unroll
        for (int q = 0; q < 4; ++q) {
            float4 o;
            o.x = tanh_f(acc[q][0] + bb.x); o.y = tanh_f(acc[q][1] + bb.y);
            o.z = tanh_f(acc[q][2] + bb.z); o.w = tanh_f(acc[q][3] + bb.w);
            st4(&Abuf[s0 + q][j4], o);
        }
    }

    // ---- L6 + L7: h2 = tanh(Abuf @ aW2 + ab2); score = h2 @ aW3 + ab3
    zero_acc(acc);
    #pragma unroll
    for (int ch = 0; ch < 2; ++ch) {
        __syncthreads();
        stage_w<64>(Wbuf, aW2 + ch * 64 * HID, tid);
        __syncthreads();
        accum_rows<64, HID>(acc, Wbuf, &Abuf[0][0], s0, ch * 64, j4);
    }
    {
        float4 bb  = ld4(&ab2[j4]);
        float4 w3v = ld4(&aW3[j4]);
        float part[4];
        #pragma unroll
        for (int q = 0; q < 4; ++q) {
            float h0 = tanh_f(acc[q][0] + bb.x);
            float h1 = tanh_f(acc[q][1] + bb.y);
            float h2 = tanh_f(acc[q][2] + bb.z);
            float h3 = tanh_f(acc[q][3] + bb.w);
            part[q] = h0 * w3v.x + h1 * w3v.y + h2 * w3v.z + h3 * w3v.w;
        }
        #pragma unroll
        for (int m = 1; m <= 16; m <<= 1) {
            #pragma unroll
            for (int q = 0; q < 4; ++q) part[q] += __shfl_xor(part[q], m);
        }
        __syncthreads();   // Mrow in Ubuf now dead; safe to write scoreb
        if (jg == 0) {
            float b3 = ab3[0];
            #pragma unroll
            for (int q = 0; q < 4; ++q) scoreb[s0 + q] = part[q] + b3;
        }
    }
    __syncthreads();

    // ---- softmax per group (8 scores each)
    if (tid < NGRP) {
        float mx = -1e30f;
        #pragma unroll
        for (int k = 0; k < 8; ++k) mx = fmaxf(mx, scoreb[tid * 8 + k]);
        float es[8]; float ssum = 0.f;
        #pragma unroll
        for (int k = 0; k < 8; ++k) { es[k] = __expf(scoreb[tid * 8 + k] - mx); ssum += es[k]; }
        float inv = 1.f / ssum;
        #pragma unroll
        for (int k = 0; k < 8; ++k) attnb[tid * 8 + k] = es[k] * inv;
    }

    // ---- L3: Ebuf @ vW1 -> tanh -> Abuf
    zero_acc(acc);
    #pragma unroll
    for (int ch = 0; ch < 2; ++ch) {
        __syncthreads();
        stage_w<64>(Wbuf, vW1 + ch * 64 * HID, tid);
        __syncthreads();
        accum_rows<64, HID>(acc, Wbuf, &Ebuf[0][0], s0, ch * 64, j4);
    }
    {
        float4 bb = ld4(&vb1[j4]);
        #pragma unroll
        for (int q = 0; q < 4; ++q) {
            float4 o;
            o.x = tanh_f(acc[q][0] + bb.x); o.y = tanh_f(acc[q][1] + bb.y);
            o.z = tanh_f(acc[q][2] + bb.z); o.w = tanh_f(acc[q][3] + bb.w);
            st4(&Abuf[s0 + q][j4], o);
        }
    }

    // ---- L4: vals = tanh(Abuf @ vW2 + vb2); out[b] = sum_k attn*vals (fused)
    zero_acc(acc);
    #pragma unroll
    for (int ch = 0; ch < 2; ++ch) {
        __syncthreads();
        stage_w<64>(Wbuf, vW2 + ch * 64 * HID, tid);
        __syncthreads();
        accum_rows<64, HID>(acc, Wbuf, &Abuf[0][0], s0, ch * 64, j4);
    }
    {
        float4 bb = ld4(&vb2[j4]);
        float o0 = 0.f, o1 = 0.f, o2 = 0.f, o3 = 0.f;
        #pragma unroll
        for (int q = 0; q < 4; ++q) {
            float a = attnb[s0 + q];
            o0 += a * tanh_f(acc[q][0] + bb.x);
            o1 += a * tanh_f(acc[q][1] + bb.y);
            o2 += a * tanh_f(acc[q][2] + bb.z);
            o3 += a * tanh_f(acc[q][3] + bb.w);
        }
        // combine the two 4-row halves of each group (lanes l and l^32 of a wave)
        o0 += __shfl_xor(o0, 32); o1 += __shfl_xor(o1, 32);
        o2 += __shfl_xor(o2, 32); o3 += __shfl_xor(o3, 32);
        if ((tid & 63) < 32) {
            int b = blockIdx.x * NGRP + (tid >> 6);   // wave id == local group id
            st4(&out[b * HID + j4], make_float4(o0, o1, o2, o3));
        }
    }
}

extern "C" void kernel_launch(void* const* d_in, const int* in_sizes, int n_in,
                              void* d_out, int out_size, void* d_ws, size_t ws_size,
                              hipStream_t stream) {
    const float* self_obs = (const float*)d_in[0];
    const float* obs      = (const float*)d_in[1];
    const float* eW1 = (const float*)d_in[2];  const float* eb1 = (const float*)d_in[3];
    const float* eW2 = (const float*)d_in[4];  const float* eb2 = (const float*)d_in[5];
    const float* vW1 = (const float*)d_in[6];  const float* vb1 = (const float*)d_in[7];
    const float* vW2 = (const float*)d_in[8];  const float* vb2 = (const float*)d_in[9];
    const float* aW1 = (const float*)d_in[10]; const float* ab1 = (const float*)d_in[11];
    const float* aW2 = (const float*)d_in[12]; const float* ab2 = (const float*)d_in[13];
    const float* aW3 = (const float*)d_in[14]; const float* ab3 = (const float*)d_in[15];
    float* out = (float*)d_out;
    float* meanbuf = (float*)d_ws;   // BATCH x HID floats = 33.5 MB

    const int total_rows = BATCH * 8;
    dim3 grid(total_rows / RB);   // 16384

    emb_mean_k<<<grid, NTHREADS, 0, stream>>>(self_obs, obs, eW1, eb1, eW2, eb2, meanbuf);
    quad_attn_main<<<grid, NTHREADS, 0, stream>>>(
        self_obs, obs, eW1, eb1, eW2, eb2, vW1, vb1, vW2, vb2,
        aW1, ab1, aW2, ab2, aW3, ab3, meanbuf, out);
}

// Round 3
// 958.653 us; speedup vs baseline: 2.3514x; 2.3514x over previous
//
#include <hip/hip_runtime.h>
#include <math.h>

#define BATCH    65536
#define HID      128
#define SELF_DIM 18
#define NBR_DIM  6
#define OBS_W    66
#define RB       64      // rows per block
#define NTHREADS 256
#define X0S      48      // padded LDS stride for the 24-wide input (16B-aligned rows)

using bf16x8 = __attribute__((ext_vector_type(8))) short;
using f32x4  = __attribute__((ext_vector_type(4))) float;

// ---- ws layout (element offsets into a short*) ----
#define E1H 0            // eW1^T hi  [128][32]
#define E1L 4096
#define E2H 8192         // eW2^T hi  [128][128]
#define E2L 24576
#define V1H 40960
#define V1L 57344
#define V2H 73728
#define V2L 90112
#define A1H 106496       // aW1^T hi  [128][256]
#define A1L 139264
#define A2H 172032
#define A2L 188416
#define MEANH 204800     // mean hi   [BATCH][128]
#define MEANL (MEANH + BATCH*HID)
#define WS_ELEMS_FULL (MEANL + BATCH*HID)

__device__ __forceinline__ unsigned short f2bf(float f) {
    unsigned u = __float_as_uint(f);
    u += 0x7fffu + ((u >> 16) & 1u);      // RNE
    return (unsigned short)(u >> 16);
}
__device__ __forceinline__ float bf2f(unsigned short h) {
    return __uint_as_float(((unsigned)h) << 16);
}
__device__ __forceinline__ void splitbf(float x, unsigned short& h, unsigned short& l) {
    h = f2bf(x);
    l = f2bf(x - bf2f(h));
}
__device__ __forceinline__ float tanh_f(float x) {
    x = fminf(15.f, fmaxf(-15.f, x));
    float t = __expf(2.f * x);
    return (t - 1.f) / (t + 1.f);
}
__device__ __forceinline__ f32x4 mfma16(bf16x8 a, bf16x8 b, f32x4 c) {
    return __builtin_amdgcn_mfma_f32_16x16x32_bf16(a, b, c, 0, 0, 0);
}
__device__ __forceinline__ void zacc(f32x4 acc[4][2]) {
    #pragma unroll
    for (int rt = 0; rt < 4; ++rt) {
        acc[rt][0] = f32x4{0.f, 0.f, 0.f, 0.f};
        acc[rt][1] = f32x4{0.f, 0.f, 0.f, 0.f};
    }
}

// D[64x128-slice] += X[64xK] * W[Kx128], wave owns cols [wcol0, wcol0+32).
// X in LDS as bf16 hi/lo, row-major stride XSTR, optional (r&7)<<3 element swizzle.
// W^T hi/lo in global: [128 cols][KEL k], k contiguous per col.
template<bool SWZ, int NKS, int KEL, int XSTR>
__device__ __forceinline__ void mm_lds(f32x4 acc[4][2],
        const short* Xh, const short* Xl,
        const short* __restrict__ Wh, const short* __restrict__ Wl,
        int lane, int wcol0)
{
    const int quart8 = (lane >> 4) << 3;
    const int lm = lane & 15;
    #pragma unroll
    for (int ks = 0; ks < NKS; ++ks) {
        const int k0 = ks * 32 + quart8;
        const int col0 = wcol0 + lm, col1 = wcol0 + 16 + lm;
        bf16x8 bh0 = *(const bf16x8*)(Wh + col0 * KEL + k0);
        bf16x8 bl0 = *(const bf16x8*)(Wl + col0 * KEL + k0);
        bf16x8 bh1 = *(const bf16x8*)(Wh + col1 * KEL + k0);
        bf16x8 bl1 = *(const bf16x8*)(Wl + col1 * KEL + k0);
        #pragma unroll
        for (int rt = 0; rt < 4; ++rt) {
            int r = rt * 16 + lm;
            int elem = r * XSTR + k0;
            if (SWZ) elem ^= (r & 7) << 3;
            bf16x8 ah = *(const bf16x8*)(Xh + elem);
            bf16x8 al = *(const bf16x8*)(Xl + elem);
            acc[rt][0] = mfma16(ah, bh0, acc[rt][0]);
            acc[rt][0] = mfma16(al, bh0, acc[rt][0]);
            acc[rt][0] = mfma16(ah, bl0, acc[rt][0]);
            acc[rt][1] = mfma16(ah, bh1, acc[rt][1]);
            acc[rt][1] = mfma16(al, bh1, acc[rt][1]);
            acc[rt][1] = mfma16(ah, bl1, acc[rt][1]);
        }
    }
}

// tanh(acc + bias) -> split -> swizzled LDS store ([64][128] hi/lo)
__device__ __forceinline__ void epi_tanh_store(f32x4 acc[4][2], const float* __restrict__ bias,
        short* Xh, short* Xl, int lane, int wcol0)
{
    const int q = lane >> 4;
    #pragma unroll
    for (int ct = 0; ct < 2; ++ct) {
        int c = wcol0 + ct * 16 + (lane & 15);
        float b = bias[c];
        #pragma unroll
        for (int rt = 0; rt < 4; ++rt) {
            #pragma unroll
            for (int reg = 0; reg < 4; ++reg) {
                int r = rt * 16 + q * 4 + reg;
                float v = tanh_f(acc[rt][ct][reg] + b);
                unsigned short h, l; splitbf(v, h, l);
                int elem = (r * HID + c) ^ ((r & 7) << 3);
                Xh[elem] = (short)h; Xl[elem] = (short)l;
            }
        }
    }
}

// build X0 rows r0..r0+63: [self_obs[r%B] | obs[r/8] nbr slice | zeros], split hi/lo
__device__ __forceinline__ void build_x0(short* X0h, short* X0l,
        const float* __restrict__ self_obs, const float* __restrict__ obs,
        int r0, int tid)
{
    for (int idx = tid; idx < RB * X0S; idx += NTHREADS) {
        int s = idx / X0S, c = idx - s * X0S;
        int r = r0 + s;
        float v = 0.f;
        if (c < SELF_DIM)      v = self_obs[(size_t)(r & (BATCH - 1)) * SELF_DIM + c];
        else if (c < 24)       v = obs[(size_t)(r >> 3) * OBS_W + SELF_DIM + (r & 7) * NBR_DIM + (c - SELF_DIM)];
        unsigned short h, l; splitbf(v, h, l);
        X0h[idx] = (short)h; X0l[idx] = (short)l;
    }
}

// ================= prep: W -> W^T bf16 hi/lo in ws =================
__global__ void prep_w(const float* __restrict__ eW1, const float* __restrict__ eW2,
                       const float* __restrict__ vW1, const float* __restrict__ vW2,
                       const float* __restrict__ aW1, const float* __restrict__ aW2,
                       short* __restrict__ ws)
{
    int t = blockIdx.x * blockDim.x + threadIdx.x;
    float v; int dh, dl;
    if (t < 4096)        { int u = t;          int c = u >> 5, k = u & 31;
                           v = (k < 24) ? eW1[k * HID + c] : 0.f; dh = E1H + u; dl = E1L + u; }
    else if (t < 20480)  { int u = t - 4096;   int c = u >> 7, k = u & 127;
                           v = eW2[k * HID + c]; dh = E2H + u; dl = E2L + u; }
    else if (t < 36864)  { int u = t - 20480;  int c = u >> 7, k = u & 127;
                           v = vW1[k * HID + c]; dh = V1H + u; dl = V1L + u; }
    else if (t < 53248)  { int u = t - 36864;  int c = u >> 7, k = u & 127;
                           v = vW2[k * HID + c]; dh = V2H + u; dl = V2L + u; }
    else if (t < 86016)  { int u = t - 53248;  int c = u >> 8, k = u & 255;
                           v = aW1[k * HID + c]; dh = A1H + u; dl = A1L + u; }
    else if (t < 102400) { int u = t - 86016;  int c = u >> 7, k = u & 127;
                           v = aW2[k * HID + c]; dh = A2H + u; dl = A2L + u; }
    else return;
    unsigned short h, l; splitbf(v, h, l);
    ws[dh] = (short)h; ws[dl] = (short)l;
}

// ================= kernel A: emb -> group means (bf16 hi/lo to ws) =================
__global__ __launch_bounds__(NTHREADS, 2)
void qk_mean(const float* __restrict__ self_obs, const float* __restrict__ obs,
             const float* __restrict__ eb1, const float* __restrict__ eb2,
             short* __restrict__ ws, int use_ml)
{
    __shared__ __align__(16) short X0h[RB * X0S], X0l[RB * X0S];
    __shared__ __align__(16) short XPh[RB * HID], XPl[RB * HID];

    const int tid = threadIdx.x, lane = tid & 63, w = tid >> 6;
    const int wcol0 = w * 32;
    const int r0 = blockIdx.x * RB;

    build_x0(X0h, X0l, self_obs, obs, r0, tid);
    __syncthreads();

    f32x4 acc[4][2];
    // L1
    zacc(acc);
    mm_lds<false, 1, 32, X0S>(acc, X0h, X0l, ws + E1H, ws + E1L, lane, wcol0);
    epi_tanh_store(acc, eb1, XPh, XPl, lane, wcol0);
    __syncthreads();
    // L2
    zacc(acc);
    mm_lds<true, 4, 128, HID>(acc, XPh, XPl, ws + E2H, ws + E2L, lane, wcol0);

    // mean epilogue: tanh, sum 8 consecutive rows, /8, split, store global
    short* mh = ws + MEANH;
    short* mlp = ws + MEANL;
    const int q = lane >> 4;
    #pragma unroll
    for (int ct = 0; ct < 2; ++ct) {
        int c = wcol0 + ct * 16 + (lane & 15);
        float b = eb2[c];
        #pragma unroll
        for (int rt = 0; rt < 4; ++rt) {
            float s = 0.f;
            #pragma unroll
            for (int reg = 0; reg < 4; ++reg) s += tanh_f(acc[rt][ct][reg] + b);
            s += __shfl_xor(s, 16);          // q0+=q1 (rows 0-7), q2+=q3 (rows 8-15)
            float m = s * 0.125f;
            unsigned short h, l; splitbf(m, h, l);
            if (q == 0 || q == 2) {
                size_t g = (size_t)blockIdx.x * 8 + 2 * rt + (q >> 1);
                mh[g * HID + c] = (short)h;
                if (use_ml) mlp[g * HID + c] = (short)l;
            }
        }
    }
}

// ================= kernel B: full pipeline =================
__global__ __launch_bounds__(NTHREADS, 2)
void qk_main(const float* __restrict__ self_obs, const float* __restrict__ obs,
             const float* __restrict__ eb1, const float* __restrict__ eb2,
             const float* __restrict__ vb1, const float* __restrict__ vb2,
             const float* __restrict__ ab1, const float* __restrict__ ab2,
             const float* __restrict__ aW3, const float* __restrict__ ab3,
             const short* __restrict__ ws, float* __restrict__ out, int use_ml)
{
    __shared__ __align__(16) short X0h[RB * X0S], X0l[RB * X0S];   // 12.0 KB
    __shared__ __align__(16) short XPh[RB * HID], XPl[RB * HID];   // 32 KB
    __shared__ __align__(16) short Eh[RB * HID],  El[RB * HID];    // 32 KB
    __shared__ float spart[4][RB];
    __shared__ float scoresb[RB];
    __shared__ float attnb[RB];

    const int tid = threadIdx.x, lane = tid & 63, w = tid >> 6;
    const int wcol0 = w * 32;
    const int r0 = blockIdx.x * RB;
    const int q = lane >> 4;

    build_x0(X0h, X0l, self_obs, obs, r0, tid);
    __syncthreads();

    f32x4 acc[4][2];

    // ---- L1: X0 @ eW1 -> tanh -> XP
    zacc(acc);
    mm_lds<false, 1, 32, X0S>(acc, X0h, X0l, ws + E1H, ws + E1L, lane, wcol0);
    epi_tanh_store(acc, eb1, XPh, XPl, lane, wcol0);
    __syncthreads();

    // ---- L2: XP @ eW2 -> tanh -> E (emb)
    zacc(acc);
    mm_lds<true, 4, 128, HID>(acc, XPh, XPl, ws + E2H, ws + E2L, lane, wcol0);
    epi_tanh_store(acc, eb2, Eh, El, lane, wcol0);
    __syncthreads();

    // ---- L5: tanh([emb | mean] @ aW1 + ab1) -> XP
    zacc(acc);
    mm_lds<true, 4, 256, HID>(acc, Eh, El, ws + A1H, ws + A1L, lane, wcol0);
    {   // mean half: A-frags straight from global means (row = (r0+r) % B)
        const short* __restrict__ mh = ws + MEANH;
        const short* __restrict__ mlp = ws + MEANL;
        const int quart8 = (lane >> 4) << 3;
        const int lm = lane & 15;
        #pragma unroll
        for (int ks2 = 0; ks2 < 4; ++ks2) {
            const int km = ks2 * 32 + quart8;
            const int kw = 128 + km;
            const int col0 = wcol0 + lm, col1 = wcol0 + 16 + lm;
            bf16x8 bh0 = *(const bf16x8*)(ws + A1H + col0 * 256 + kw);
            bf16x8 bl0 = *(const bf16x8*)(ws + A1L + col0 * 256 + kw);
            bf16x8 bh1 = *(const bf16x8*)(ws + A1H + col1 * 256 + kw);
            bf16x8 bl1 = *(const bf16x8*)(ws + A1L + col1 * 256 + kw);
            #pragma unroll
            for (int rt = 0; rt < 4; ++rt) {
                int mrow = (r0 + rt * 16 + lm) & (BATCH - 1);
                bf16x8 ah = *(const bf16x8*)(mh + (size_t)mrow * HID + km);
                acc[rt][0] = mfma16(ah, bh0, acc[rt][0]);
                acc[rt][0] = mfma16(ah, bl0, acc[rt][0]);
                acc[rt][1] = mfma16(ah, bh1, acc[rt][1]);
                acc[rt][1] = mfma16(ah, bl1, acc[rt][1]);
                if (use_ml) {
                    bf16x8 al = *(const bf16x8*)(mlp + (size_t)mrow * HID + km);
                    acc[rt][0] = mfma16(al, bh0, acc[rt][0]);
                    acc[rt][1] = mfma16(al, bh1, acc[rt][1]);
                }
            }
        }
    }
    epi_tanh_store(acc, ab1, XPh, XPl, lane, wcol0);
    __syncthreads();

    // ---- L6+L7: h2 = tanh(XP @ aW2 + ab2); score partials = (h2 . aW3)
    zacc(acc);
    mm_lds<true, 4, 128, HID>(acc, XPh, XPl, ws + A2H, ws + A2L, lane, wcol0);
    {
        int c0 = wcol0 + (lane & 15), c1 = c0 + 16;
        float b20 = ab2[c0], b21 = ab2[c1];
        float w30 = aW3[c0], w31 = aW3[c1];
        #pragma unroll
        for (int rt = 0; rt < 4; ++rt) {
            float p[4];
            #pragma unroll
            for (int reg = 0; reg < 4; ++reg)
                p[reg] = tanh_f(acc[rt][0][reg] + b20) * w30
                       + tanh_f(acc[rt][1][reg] + b21) * w31;
            #pragma unroll
            for (int m = 1; m <= 8; m <<= 1) {
                #pragma unroll
                for (int reg = 0; reg < 4; ++reg) p[reg] += __shfl_xor(p[reg], m);
            }
            if ((lane & 15) == 0) {
                #pragma unroll
                for (int reg = 0; reg < 4; ++reg)
                    spart[w][rt * 16 + q * 4 + reg] = p[reg];
            }
        }
    }
    __syncthreads();

    // ---- scores + softmax (per group of 8 rows)
    if (tid < RB) scoresb[tid] = spart[0][tid] + spart[1][tid] + spart[2][tid] + spart[3][tid] + ab3[0];
    __syncthreads();
    if (tid < 8) {
        float mx = -1e30f;
        #pragma unroll
        for (int k = 0; k < 8; ++k) mx = fmaxf(mx, scoresb[tid * 8 + k]);
        float es[8], ssum = 0.f;
        #pragma unroll
        for (int k = 0; k < 8; ++k) { es[k] = __expf(scoresb[tid * 8 + k] - mx); ssum += es[k]; }
        float inv = 1.f / ssum;
        #pragma unroll
        for (int k = 0; k < 8; ++k) attnb[tid * 8 + k] = es[k] * inv;
    }
    __syncthreads();

    // ---- L3: E @ vW1 -> tanh -> XP
    zacc(acc);
    mm_lds<true, 4, 128, HID>(acc, Eh, El, ws + V1H, ws + V1L, lane, wcol0);
    epi_tanh_store(acc, vb1, XPh, XPl, lane, wcol0);
    __syncthreads();

    // ---- L4: vals = tanh(XP @ vW2 + vb2); out = sum_group attn * vals
    zacc(acc);
    mm_lds<true, 4, 128, HID>(acc, XPh, XPl, ws + V2H, ws + V2L, lane, wcol0);
    #pragma unroll
    for (int ct = 0; ct < 2; ++ct) {
        int c = wcol0 + ct * 16 + (lane & 15);
        float b = vb2[c];
        #pragma unroll
        for (int rt = 0; rt < 4; ++rt) {
            float s = 0.f;
            #pragma unroll
            for (int reg = 0; reg < 4; ++reg) {
                int r = rt * 16 + q * 4 + reg;
                s += attnb[r] * tanh_f(acc[rt][ct][reg] + b);
            }
            s += __shfl_xor(s, 16);          // combine rows 0-3/4-7 and 8-11/12-15
            if (q == 0 || q == 2) {
                size_t bidx = (size_t)blockIdx.x * 8 + 2 * rt + (q >> 1);
                out[bidx * HID + c] = s;
            }
        }
    }
}

extern "C" void kernel_launch(void* const* d_in, const int* in_sizes, int n_in,
                              void* d_out, int out_size, void* d_ws, size_t ws_size,
                              hipStream_t stream) {
    const float* self_obs = (const float*)d_in[0];
    const float* obs      = (const float*)d_in[1];
    const float* eW1 = (const float*)d_in[2];  const float* eb1 = (const float*)d_in[3];
    const float* eW2 = (const float*)d_in[4];  const float* eb2 = (const float*)d_in[5];
    const float* vW1 = (const float*)d_in[6];  const float* vb1 = (const float*)d_in[7];
    const float* vW2 = (const float*)d_in[8];  const float* vb2 = (const float*)d_in[9];
    const float* aW1 = (const float*)d_in[10]; const float* ab1 = (const float*)d_in[11];
    const float* aW2 = (const float*)d_in[12]; const float* ab2 = (const float*)d_in[13];
    const float* aW3 = (const float*)d_in[14]; const float* ab3 = (const float*)d_in[15];
    float* out = (float*)d_out;
    short* ws = (short*)d_ws;

    int use_ml = (ws_size >= (size_t)WS_ELEMS_FULL * sizeof(short)) ? 1 : 0;

    prep_w<<<400, 256, 0, stream>>>(eW1, eW2, vW1, vW2, aW1, aW2, ws);

    dim3 grid(BATCH * 8 / RB);   // 8192
    qk_mean<<<grid, NTHREADS, 0, stream>>>(self_obs, obs, eb1, eb2, ws, use_ml);
    qk_main<<<grid, NTHREADS, 0, stream>>>(self_obs, obs, eb1, eb2, vb1, vb2,
                                           ab1, ab2, aW3, ab3, ws, out, use_ml);
}

// Round 4
// 726.647 us; speedup vs baseline: 3.1022x; 1.3193x over previous
//
#include <hip/hip_runtime.h>
#include <math.h>

#define BATCH    65536
#define HID      128
#define SELF_DIM 18
#define NBR_DIM  6
#define OBS_W    66
#define RB       64      // rows per block
#define NTHREADS 256
#define X0S      32      // pow2 LDS stride for the 24-wide input (zero-padded)

using bf16x8 = __attribute__((ext_vector_type(8))) short;
using f32x4  = __attribute__((ext_vector_type(4))) float;

// ---- ws layout (element offsets into a short*) ----
#define E1H 0            // eW1^T hi  [128][32]
#define E1L 4096
#define E2H 8192         // eW2^T hi  [128][128]
#define E2L 24576
#define V1H 40960
#define V1L 57344
#define V2H 73728
#define V2L 90112
#define A1H 106496       // aW1^T hi  [128][256]
#define A1L 139264
#define A2H 172032
#define A2L 188416
#define MEANH 204800     // mean hi   [BATCH][128]
#define MEANL (MEANH + BATCH*HID)
#define WS_ELEMS_FULL (MEANL + BATCH*HID)

__device__ __forceinline__ float4 ld4(const float* p) { return *reinterpret_cast<const float4*>(p); }

// tanh = 1 - 2/(e^{2x}+1); inf-safe (x->+inf: rcp(inf)=0 -> 1; x->-inf: rcp(1)=1 -> -1)
__device__ __forceinline__ float tanh_f(float x) {
    float t = __expf(2.f * x);
    float r = __builtin_amdgcn_rcpf(t + 1.f);
    return 1.f - 2.f * r;
}

__device__ __forceinline__ unsigned rne_hi(float x) {   // RNE bf16 of x, as u16 in low bits
    unsigned u = __float_as_uint(x);
    return (u + 0x7fffu + ((u >> 16) & 1u)) >> 16;
}

struct SplitPack { uint2 h, l; };
// split 4 f32 (consecutive channels) into packed bf16 hi (RNE) + lo (trunc)
__device__ __forceinline__ SplitPack split4(f32x4 v) {
    unsigned h0 = rne_hi(v[0]), h1 = rne_hi(v[1]), h2 = rne_hi(v[2]), h3 = rne_hi(v[3]);
    SplitPack sp;
    sp.h.x = h0 | (h1 << 16);
    sp.h.y = h2 | (h3 << 16);
    float f0 = __uint_as_float(h0 << 16), f1 = __uint_as_float(h1 << 16);
    float f2 = __uint_as_float(h2 << 16), f3 = __uint_as_float(h3 << 16);
    unsigned l0 = __float_as_uint(v[0] - f0), l1 = __float_as_uint(v[1] - f1);
    unsigned l2 = __float_as_uint(v[2] - f2), l3 = __float_as_uint(v[3] - f3);
    sp.l.x = (l0 >> 16) | (l1 & 0xffff0000u);
    sp.l.y = (l2 >> 16) | (l3 & 0xffff0000u);
    return sp;
}

__device__ __forceinline__ f32x4 mfma16(bf16x8 a, bf16x8 b, f32x4 c) {
    return __builtin_amdgcn_mfma_f32_16x16x32_bf16(a, b, c, 0, 0, 0);
}
__device__ __forceinline__ void zacc(f32x4 acc[4][2]) {
    #pragma unroll
    for (int rt = 0; rt < 4; ++rt) {
        acc[rt][0] = f32x4{0.f, 0.f, 0.f, 0.f};
        acc[rt][1] = f32x4{0.f, 0.f, 0.f, 0.f};
    }
}

// All-T matmul: acc[rt][ct] (+)= W^T[j-tile ct][k] * X^T[k][r-tile rt]
// A-frag: W^T hi/lo global [128 j][KEL k], k contiguous. B-frag: X hi/lo LDS [64 r][XSTR k].
// 3-term split, term-major (reuse distance 8 across the 8 accumulators).
template<bool SWZ, int NKS, int KEL, int XSTR>
__device__ __forceinline__ void mmT(f32x4 acc[4][2],
        const short* Xh, const short* Xl,
        const short* __restrict__ Wh, const short* __restrict__ Wl,
        int lane, int wcol0)
{
    const int q8 = (lane >> 4) << 3;
    const int lm = lane & 15;
    #pragma unroll
    for (int ks = 0; ks < NKS; ++ks) {
        const int k0 = ks * 32 + q8;
        const int c0 = wcol0 + lm, c1 = c0 + 16;
        bf16x8 wh0 = *(const bf16x8*)(Wh + c0 * KEL + k0);
        bf16x8 wh1 = *(const bf16x8*)(Wh + c1 * KEL + k0);
        bf16x8 wl0 = *(const bf16x8*)(Wl + c0 * KEL + k0);
        bf16x8 wl1 = *(const bf16x8*)(Wl + c1 * KEL + k0);
        bf16x8 xh[4], xl[4];
        #pragma unroll
        for (int rt = 0; rt < 4; ++rt) {
            int r = rt * 16 + lm;
            int e = r * XSTR + k0;
            if (SWZ) e ^= (r & 7) << 3;
            xh[rt] = *(const bf16x8*)(Xh + e);
            xl[rt] = *(const bf16x8*)(Xl + e);
        }
        __builtin_amdgcn_s_setprio(1);
        #pragma unroll
        for (int rt = 0; rt < 4; ++rt) {
            acc[rt][0] = mfma16(wh0, xh[rt], acc[rt][0]);
            acc[rt][1] = mfma16(wh1, xh[rt], acc[rt][1]);
        }
        #pragma unroll
        for (int rt = 0; rt < 4; ++rt) {
            acc[rt][0] = mfma16(wh0, xl[rt], acc[rt][0]);
            acc[rt][1] = mfma16(wh1, xl[rt], acc[rt][1]);
        }
        #pragma unroll
        for (int rt = 0; rt < 4; ++rt) {
            acc[rt][0] = mfma16(wl0, xh[rt], acc[rt][0]);
            acc[rt][1] = mfma16(wl1, xh[rt], acc[rt][1]);
        }
        __builtin_amdgcn_s_setprio(0);
    }
}

// tanh(acc + bias) -> split -> packed b64 stores into swizzled [64 r][128 k] hi/lo
__device__ __forceinline__ void epi_tanh_storeT(f32x4 acc[4][2], const float* __restrict__ bias,
        short* Xh, short* Xl, int lane, int wcol0)
{
    const int q = lane >> 4, lm = lane & 15;
    #pragma unroll
    for (int ct = 0; ct < 2; ++ct) {
        const int j0 = wcol0 + ct * 16 + q * 4;
        float4 bb = ld4(&bias[j0]);
        #pragma unroll
        for (int rt = 0; rt < 4; ++rt) {
            int r = rt * 16 + lm;
            f32x4 v;
            v[0] = tanh_f(acc[rt][ct][0] + bb.x);
            v[1] = tanh_f(acc[rt][ct][1] + bb.y);
            v[2] = tanh_f(acc[rt][ct][2] + bb.z);
            v[3] = tanh_f(acc[rt][ct][3] + bb.w);
            SplitPack sp = split4(v);
            int e = (r * HID + j0) ^ ((r & 7) << 3);
            *reinterpret_cast<uint2*>(Xh + e) = sp.h;
            *reinterpret_cast<uint2*>(Xl + e) = sp.l;
        }
    }
}

// build X0 rows r0..r0+63: [self_obs[r%B] | obs[r/8] nbr slice | zeros], split hi/lo
__device__ __forceinline__ void build_x0(short* X0h, short* X0l,
        const float* __restrict__ self_obs, const float* __restrict__ obs,
        int r0, int tid)
{
    for (int idx = tid; idx < RB * X0S; idx += NTHREADS) {
        int s = idx >> 5, c = idx & 31;
        int r = r0 + s;
        float v = 0.f;
        if (c < SELF_DIM) v = self_obs[(size_t)(r & (BATCH - 1)) * SELF_DIM + c];
        else if (c < 24)  v = obs[(size_t)(r >> 3) * OBS_W + SELF_DIM + (r & 7) * NBR_DIM + (c - SELF_DIM)];
        unsigned u = __float_as_uint(v);
        unsigned h = (u + 0x7fffu + ((u >> 16) & 1u)) >> 16;
        float lf = v - __uint_as_float(h << 16);
        X0h[idx] = (short)h;
        X0l[idx] = (short)(__float_as_uint(lf) >> 16);
    }
}

// ================= prep: W -> W^T bf16 hi/lo in ws =================
__global__ void prep_w(const float* __restrict__ eW1, const float* __restrict__ eW2,
                       const float* __restrict__ vW1, const float* __restrict__ vW2,
                       const float* __restrict__ aW1, const float* __restrict__ aW2,
                       short* __restrict__ ws)
{
    int t = blockIdx.x * blockDim.x + threadIdx.x;
    float v; int dh, dl;
    if (t < 4096)        { int u = t;          int c = u >> 5, k = u & 31;
                           v = (k < 24) ? eW1[k * HID + c] : 0.f; dh = E1H + u; dl = E1L + u; }
    else if (t < 20480)  { int u = t - 4096;   int c = u >> 7, k = u & 127;
                           v = eW2[k * HID + c]; dh = E2H + u; dl = E2L + u; }
    else if (t < 36864)  { int u = t - 20480;  int c = u >> 7, k = u & 127;
                           v = vW1[k * HID + c]; dh = V1H + u; dl = V1L + u; }
    else if (t < 53248)  { int u = t - 36864;  int c = u >> 7, k = u & 127;
                           v = vW2[k * HID + c]; dh = V2H + u; dl = V2L + u; }
    else if (t < 86016)  { int u = t - 53248;  int c = u >> 8, k = u & 255;
                           v = aW1[k * HID + c]; dh = A1H + u; dl = A1L + u; }
    else if (t < 102400) { int u = t - 86016;  int c = u >> 7, k = u & 127;
                           v = aW2[k * HID + c]; dh = A2H + u; dl = A2L + u; }
    else return;
    unsigned uu = __float_as_uint(v);
    unsigned h = (uu + 0x7fffu + ((uu >> 16) & 1u)) >> 16;
    float lf = v - __uint_as_float(h << 16);
    ws[dh] = (short)h;
    ws[dl] = (short)(__float_as_uint(lf) >> 16);
}

// bijective block remap: the 8 blocks spaced 1024 apart share mean/self rows -> run together
__device__ __forceinline__ int remap_bid(int b) { return ((b & 7) << 10) | (b >> 3); }

// ================= kernel A: emb -> group means (bf16 hi/lo to ws) =================
__global__ __launch_bounds__(NTHREADS, 2)
void qk_mean(const float* __restrict__ self_obs, const float* __restrict__ obs,
             const float* __restrict__ eb1, const float* __restrict__ eb2,
             short* __restrict__ ws, int use_ml)
{
    __shared__ __align__(16) short X0h[RB * X0S], X0l[RB * X0S];
    __shared__ __align__(16) short XPh[RB * HID], XPl[RB * HID];

    const int tid = threadIdx.x, lane = tid & 63, w = tid >> 6;
    const int wcol0 = w * 32;
    const int bidx = remap_bid(blockIdx.x);
    const int r0 = bidx * RB;
    const int q = lane >> 4, lm = lane & 15;

    build_x0(X0h, X0l, self_obs, obs, r0, tid);
    __syncthreads();

    f32x4 acc[4][2];
    // L1
    zacc(acc);
    mmT<false, 1, 32, X0S>(acc, X0h, X0l, ws + E1H, ws + E1L, lane, wcol0);
    epi_tanh_storeT(acc, eb1, XPh, XPl, lane, wcol0);
    __syncthreads();
    // L2 -> emb, reduce to group means in-register
    zacc(acc);
    mmT<true, 4, 128, HID>(acc, XPh, XPl, ws + E2H, ws + E2L, lane, wcol0);

    short* mh  = ws + MEANH;
    short* mlp = ws + MEANL;
    #pragma unroll
    for (int ct = 0; ct < 2; ++ct) {
        const int j0 = wcol0 + ct * 16 + q * 4;
        float4 bb = ld4(&eb2[j0]);
        #pragma unroll
        for (int rt = 0; rt < 4; ++rt) {
            f32x4 v;
            v[0] = tanh_f(acc[rt][ct][0] + bb.x);
            v[1] = tanh_f(acc[rt][ct][1] + bb.y);
            v[2] = tanh_f(acc[rt][ct][2] + bb.z);
            v[3] = tanh_f(acc[rt][ct][3] + bb.w);
            #pragma unroll
            for (int m = 1; m <= 4; m <<= 1) {
                v[0] += __shfl_xor(v[0], m); v[1] += __shfl_xor(v[1], m);
                v[2] += __shfl_xor(v[2], m); v[3] += __shfl_xor(v[3], m);
            }
            if ((lm & 7) == 0) {
                v[0] *= 0.125f; v[1] *= 0.125f; v[2] *= 0.125f; v[3] *= 0.125f;
                SplitPack sp = split4(v);
                size_t g = (size_t)bidx * 8 + rt * 2 + (lm >> 3);
                *reinterpret_cast<uint2*>(mh + g * HID + j0) = sp.h;
                if (use_ml) *reinterpret_cast<uint2*>(mlp + g * HID + j0) = sp.l;
            }
        }
    }
}

// ================= kernel B: full pipeline =================
__global__ __launch_bounds__(NTHREADS, 2)
void qk_main(const float* __restrict__ self_obs, const float* __restrict__ obs,
             const float* __restrict__ eb1, const float* __restrict__ eb2,
             const float* __restrict__ vb1, const float* __restrict__ vb2,
             const float* __restrict__ ab1, const float* __restrict__ ab2,
             const float* __restrict__ aW3, const float* __restrict__ ab3,
             const short* __restrict__ ws, float* __restrict__ out, int use_ml)
{
    __shared__ __align__(16) short X0h[RB * X0S], X0l[RB * X0S];   // 8 KB
    __shared__ __align__(16) short XPh[RB * HID], XPl[RB * HID];   // 32 KB
    __shared__ __align__(16) short Eh[RB * HID],  El[RB * HID];    // 32 KB
    __shared__ float spart[4][RB];
    __shared__ float scoresb[RB];
    __shared__ float attnb[RB];

    const int tid = threadIdx.x, lane = tid & 63, w = tid >> 6;
    const int wcol0 = w * 32;
    const int bidx = remap_bid(blockIdx.x);
    const int r0 = bidx * RB;
    const int q = lane >> 4, lm = lane & 15;

    build_x0(X0h, X0l, self_obs, obs, r0, tid);
    __syncthreads();

    f32x4 acc[4][2];

    // ---- L1: tanh(X0 @ eW1 + eb1) -> XP
    zacc(acc);
    mmT<false, 1, 32, X0S>(acc, X0h, X0l, ws + E1H, ws + E1L, lane, wcol0);
    epi_tanh_storeT(acc, eb1, XPh, XPl, lane, wcol0);
    __syncthreads();

    // ---- L2: tanh(XP @ eW2 + eb2) -> E (emb)
    zacc(acc);
    mmT<true, 4, 128, HID>(acc, XPh, XPl, ws + E2H, ws + E2L, lane, wcol0);
    epi_tanh_storeT(acc, eb2, Eh, El, lane, wcol0);
    __syncthreads();

    // ---- L5: tanh([emb | mean] @ aW1 + ab1) -> XP
    zacc(acc);
    mmT<true, 4, 256, HID>(acc, Eh, El, ws + A1H, ws + A1L, lane, wcol0);
    {   // mean half: B-frags straight from global means (row = (r0+r) % B)
        const short* __restrict__ mh  = ws + MEANH;
        const short* __restrict__ mlp = ws + MEANL;
        const int q8 = q << 3;
        #pragma unroll
        for (int ks = 0; ks < 4; ++ks) {
            const int km = ks * 32 + q8;       // k within mean (0..127)
            const int kw = 128 + km;           // k within aW1 rows (128..255)
            const int c0 = wcol0 + lm, c1 = c0 + 16;
            bf16x8 wh0 = *(const bf16x8*)(ws + A1H + c0 * 256 + kw);
            bf16x8 wh1 = *(const bf16x8*)(ws + A1H + c1 * 256 + kw);
            bf16x8 wl0 = *(const bf16x8*)(ws + A1L + c0 * 256 + kw);
            bf16x8 wl1 = *(const bf16x8*)(ws + A1L + c1 * 256 + kw);
            bf16x8 mhf[4], mlf[4];
            #pragma unroll
            for (int rt = 0; rt < 4; ++rt) {
                int mrow = (r0 + rt * 16 + lm) & (BATCH - 1);
                mhf[rt] = *(const bf16x8*)(mh + (size_t)mrow * HID + km);
                if (use_ml) mlf[rt] = *(const bf16x8*)(mlp + (size_t)mrow * HID + km);
            }
            __builtin_amdgcn_s_setprio(1);
            #pragma unroll
            for (int rt = 0; rt < 4; ++rt) {
                acc[rt][0] = mfma16(wh0, mhf[rt], acc[rt][0]);
                acc[rt][1] = mfma16(wh1, mhf[rt], acc[rt][1]);
            }
            #pragma unroll
            for (int rt = 0; rt < 4; ++rt) {
                acc[rt][0] = mfma16(wl0, mhf[rt], acc[rt][0]);
                acc[rt][1] = mfma16(wl1, mhf[rt], acc[rt][1]);
            }
            if (use_ml) {
                #pragma unroll
                for (int rt = 0; rt < 4; ++rt) {
                    acc[rt][0] = mfma16(wh0, mlf[rt], acc[rt][0]);
                    acc[rt][1] = mfma16(wh1, mlf[rt], acc[rt][1]);
                }
            }
            __builtin_amdgcn_s_setprio(0);
        }
    }
    epi_tanh_storeT(acc, ab1, XPh, XPl, lane, wcol0);
    __syncthreads();

    // ---- L6+L7: h2 = tanh(XP @ aW2 + ab2); score partial = h2 . aW3
    zacc(acc);
    mmT<true, 4, 128, HID>(acc, XPh, XPl, ws + A2H, ws + A2L, lane, wcol0);
    {
        float part[4];
        #pragma unroll
        for (int rt = 0; rt < 4; ++rt) part[rt] = 0.f;
        #pragma unroll
        for (int ct = 0; ct < 2; ++ct) {
            const int j0 = wcol0 + ct * 16 + q * 4;
            float4 bb = ld4(&ab2[j0]);
            float4 w3 = ld4(&aW3[j0]);
            #pragma unroll
            for (int rt = 0; rt < 4; ++rt) {
                part[rt] += tanh_f(acc[rt][ct][0] + bb.x) * w3.x
                          + tanh_f(acc[rt][ct][1] + bb.y) * w3.y
                          + tanh_f(acc[rt][ct][2] + bb.z) * w3.z
                          + tanh_f(acc[rt][ct][3] + bb.w) * w3.w;
            }
        }
        #pragma unroll
        for (int rt = 0; rt < 4; ++rt) {
            part[rt] += __shfl_xor(part[rt], 16);
            part[rt] += __shfl_xor(part[rt], 32);
        }
        if (q == 0) {
            #pragma unroll
            for (int rt = 0; rt < 4; ++rt) spart[w][rt * 16 + lm] = part[rt];
        }
    }
    __syncthreads();

    // ---- scores + softmax (per group of 8 rows)
    if (tid < RB) scoresb[tid] = spart[0][tid] + spart[1][tid] + spart[2][tid] + spart[3][tid] + ab3[0];
    __syncthreads();
    if (tid < 8) {
        float mx = -1e30f;
        #pragma unroll
        for (int k = 0; k < 8; ++k) mx = fmaxf(mx, scoresb[tid * 8 + k]);
        float es[8], ssum = 0.f;
        #pragma unroll
        for (int k = 0; k < 8; ++k) { es[k] = __expf(scoresb[tid * 8 + k] - mx); ssum += es[k]; }
        float inv = 1.f / ssum;
        #pragma unroll
        for (int k = 0; k < 8; ++k) attnb[tid * 8 + k] = es[k] * inv;
    }
    __syncthreads();

    // ---- L3: tanh(E @ vW1 + vb1) -> XP
    zacc(acc);
    mmT<true, 4, 128, HID>(acc, Eh, El, ws + V1H, ws + V1L, lane, wcol0);
    epi_tanh_storeT(acc, vb1, XPh, XPl, lane, wcol0);
    __syncthreads();

    // ---- L4: vals = tanh(XP @ vW2 + vb2); out = sum_group attn * vals
    zacc(acc);
    mmT<true, 4, 128, HID>(acc, XPh, XPl, ws + V2H, ws + V2L, lane, wcol0);
    #pragma unroll
    for (int ct = 0; ct < 2; ++ct) {
        const int j0 = wcol0 + ct * 16 + q * 4;
        float4 bb = ld4(&vb2[j0]);
        #pragma unroll
        for (int rt = 0; rt < 4; ++rt) {
            int r = rt * 16 + lm;
            float a = attnb[r];
            float s0 = a * tanh_f(acc[rt][ct][0] + bb.x);
            float s1 = a * tanh_f(acc[rt][ct][1] + bb.y);
            float s2 = a * tanh_f(acc[rt][ct][2] + bb.z);
            float s3 = a * tanh_f(acc[rt][ct][3] + bb.w);
            #pragma unroll
            for (int m = 1; m <= 4; m <<= 1) {
                s0 += __shfl_xor(s0, m); s1 += __shfl_xor(s1, m);
                s2 += __shfl_xor(s2, m); s3 += __shfl_xor(s3, m);
            }
            if ((lm & 7) == 0) {
                size_t b = (size_t)bidx * 8 + rt * 2 + (lm >> 3);
                *reinterpret_cast<float4*>(&out[b * HID + j0]) = make_float4(s0, s1, s2, s3);
            }
        }
    }
}

extern "C" void kernel_launch(void* const* d_in, const int* in_sizes, int n_in,
                              void* d_out, int out_size, void* d_ws, size_t ws_size,
                              hipStream_t stream) {
    const float* self_obs = (const float*)d_in[0];
    const float* obs      = (const float*)d_in[1];
    const float* eW1 = (const float*)d_in[2];  const float* eb1 = (const float*)d_in[3];
    const float* eW2 = (const float*)d_in[4];  const float* eb2 = (const float*)d_in[5];
    const float* vW1 = (const float*)d_in[6];  const float* vb1 = (const float*)d_in[7];
    const float* vW2 = (const float*)d_in[8];  const float* vb2 = (const float*)d_in[9];
    const float* aW1 = (const float*)d_in[10]; const float* ab1 = (const float*)d_in[11];
    const float* aW2 = (const float*)d_in[12]; const float* ab2 = (const float*)d_in[13];
    const float* aW3 = (const float*)d_in[14]; const float* ab3 = (const float*)d_in[15];
    float* out = (float*)d_out;
    short* ws = (short*)d_ws;

    int use_ml = (ws_size >= (size_t)WS_ELEMS_FULL * sizeof(short)) ? 1 : 0;

    prep_w<<<400, 256, 0, stream>>>(eW1, eW2, vW1, vW2, aW1, aW2, ws);

    dim3 grid(BATCH * 8 / RB);   // 8192
    qk_mean<<<grid, NTHREADS, 0, stream>>>(self_obs, obs, eb1, eb2, ws, use_ml);
    qk_main<<<grid, NTHREADS, 0, stream>>>(self_obs, obs, eb1, eb2, vb1, vb2,
                                           ab1, ab2, aW3, ab3, ws, out, use_ml);
}